// Round 12
// baseline (2253.474 us; speedup 1.0000x reference)
//
#include <hip/hip_runtime.h>

// Problem constants (B=64, S=512, D=512, K=4096)
#define N_ROWS 32768          // B*S
#define DIM    512
#define KCODES 4096
#define NPARTS 16
#define KPART  (KCODES / NPARTS)    // 256 codes per K-split block
#define Q_ELEMS (N_ROWS * DIM)      // 16777216
#define LOSS_OFF Q_ELEMS            // 1 float
#define IDX_OFF (Q_ELEMS + 1)       // 32768 floats

// ---------------- Kernel 0: init packed argmin keys ----------------
__global__ void k_init(unsigned long long* __restrict__ bk) {
    int i = blockIdx.x * blockDim.x + threadIdx.x;
    if (i < N_ROWS) bk[i] = 0xFFFFFFFFFFFFFFFFull;
}

// ---------------- Kernel 1a: codebook norms ||c_k||^2 (fp32) ----------------
__global__ void k_cnorm(const float* __restrict__ cb, float* __restrict__ cnorm) {
    int wave = (blockIdx.x * blockDim.x + threadIdx.x) >> 6;
    int lane = threadIdx.x & 63;
    if (wave >= KCODES) return;
    const float4* row = (const float4*)(cb + (size_t)wave * DIM);
    float4 v1 = row[lane];
    float4 v2 = row[lane + 64];
    float s = v1.x*v1.x + v1.y*v1.y + v1.z*v1.z + v1.w*v1.w
            + v2.x*v2.x + v2.y*v2.y + v2.z*v2.z + v2.w*v2.w;
    #pragma unroll
    for (int m = 32; m >= 1; m >>= 1) s += __shfl_xor(s, m);
    if (lane == 0) cnorm[wave] = s;
}

// ---------------- Kernel 1b: input row norms ||x_n||^2 (fp32) ----------------
__global__ void k_xnorm(const float* __restrict__ x, float* __restrict__ xnorm) {
    int wave = (blockIdx.x * blockDim.x + threadIdx.x) >> 6;
    int lane = threadIdx.x & 63;
    if (wave >= N_ROWS) return;
    const float4* row = (const float4*)(x + (size_t)wave * DIM);
    float4 v1 = row[lane];
    float4 v2 = row[lane + 64];
    float s = v1.x*v1.x + v1.y*v1.y + v1.z*v1.z + v1.w*v1.w
            + v2.x*v2.x + v2.y*v2.y + v2.z*v2.z + v2.w*v2.w;
    #pragma unroll
    for (int m = 32; m >= 1; m >>= 1) s += __shfl_xor(s, m);
    if (lane == 0) xnorm[wave] = s;
}

// ---------------- Kernel 2: fp32-formula distance + argmin ----------------
// dist32(n,k) = fl32( fl32(xnorm + cnorm[k]) - fl32(2 * dot(n,k)) ), dot as a
// sequential-d fp32 fma chain — bit-identical per (n,k) to the passing rounds.
// R12: 8x16 thread tile (BM=128, BN=256, 256 threads) -> LDS-read bytes/FMA
// drop 1.0 -> 0.75. R9's plateau closed as the LDS b128 return-BW roofline
// (85 B/cyc effective vs 128 B/cyc VALU demand = the measured 64-68% VALUBusy,
// occupancy-independent). All access patterns carried from R9 (measured 0
// conflicts). Part results merged via order-preserving packed atomicMin(u64):
// key = (monotone_uint(score)<<32) | k -> min score, tie -> min k.
#define BM 128
#define BN 256
#define BD 32
#define NTHR 256
#define NCH (DIM / BD)     // KPART == BN: 1 kc * 16 dc = 16 chunks

__global__ __launch_bounds__(NTHR)
void k_argmin(const float* __restrict__ x, const float* __restrict__ cb,
              const float* __restrict__ cnorm, const float* __restrict__ xnorm,
              unsigned long long* __restrict__ bestkey) {
    __shared__ float xs[BM][BD + 4];   // stride 36 floats; measured 0 conflicts (R4..R9)
    __shared__ float cs[BD][BN];       // transposed: cs[d][k], 32KB

    const int tid = threadIdx.x;
    const int ty = tid >> 4;           // 0..15
    const int tx = tid & 15;           // 0..15
    const int r0 = blockIdx.x * BM;
    const int kbase = blockIdx.y * KPART;

    // cs staging coords (R9 pattern, run twice for 256 codes)
    const int ck   = tid & 127;
    const int cdq0 = tid >> 7;         // 0..1

    float xn[8];
    #pragma unroll
    for (int i = 0; i < 8; ++i) xn[i] = xnorm[r0 + ty + 16 * i];

    float best[8];
    int   bidx[8];
    #pragma unroll
    for (int i = 0; i < 8; ++i) { best[i] = 3.4e38f; bidx[i] = kbase; }

    float acc[8][16];

    #pragma unroll 1
    for (int it = 0; it < NCH; ++it) {
        const int dc = it * BD;

        __syncthreads();   // previous chunk's readers done
        // stage x tile: 128 rows x 32 d (1024 float4, 4 per thread) — R9 pattern
        #pragma unroll
        for (int s = 0; s < 4; ++s) {
            int f = tid + s * NTHR;
            int row = f >> 3;              // 0..127
            int dq  = f & 7;               // 0..7
            *(float4*)&xs[row][dq * 4] =
                *(const float4*)(x + (size_t)(r0 + row) * DIM + dc + dq * 4);
        }
        // stage code tile transposed: 256 codes x 32 d (R9 pattern x2; 2-way writes = free)
        #pragma unroll
        for (int s = 0; s < 2; ++s) {
            int code = s * 128 + ck;
            #pragma unroll
            for (int it2 = 0; it2 < 4; ++it2) {
                int dq = cdq0 + it2 * 2;
                float4 v = *(const float4*)(cb + (size_t)(kbase + code) * DIM + dc + dq * 4);
                cs[dq * 4 + 0][code] = v.x;
                cs[dq * 4 + 1][code] = v.y;
                cs[dq * 4 + 2][code] = v.z;
                cs[dq * 4 + 3][code] = v.w;
            }
        }
        __syncthreads();   // tile ready

        if (it == 0) {
            #pragma unroll
            for (int i = 0; i < 8; ++i)
                #pragma unroll
                for (int j = 0; j < 16; ++j) acc[i][j] = 0.f;
        }

        // compute: 32 d-steps, d ascending (chain order = reference order)
        #pragma unroll
        for (int d4 = 0; d4 < 8; ++d4) {
            float4 xa[8];
            #pragma unroll
            for (int i = 0; i < 8; ++i)
                xa[i] = *(const float4*)&xs[ty + 16 * i][d4 * 4];
            #pragma unroll
            for (int dd = 0; dd < 4; ++dd) {
                int d = d4 * 4 + dd;
                float4 cv[4];
                #pragma unroll
                for (int jh = 0; jh < 4; ++jh)
                    cv[jh] = *(const float4*)&cs[d][jh * 64 + tx * 4];
                #pragma unroll
                for (int i = 0; i < 8; ++i) {
                    float a = (dd == 0) ? xa[i].x : (dd == 1) ? xa[i].y
                            : (dd == 2) ? xa[i].z : xa[i].w;   // dd compile-time
                    #pragma unroll
                    for (int jh = 0; jh < 4; ++jh) {
                        acc[i][jh * 4 + 0] = fmaf(a, cv[jh].x, acc[i][jh * 4 + 0]);
                        acc[i][jh * 4 + 1] = fmaf(a, cv[jh].y, acc[i][jh * 4 + 1]);
                        acc[i][jh * 4 + 2] = fmaf(a, cv[jh].z, acc[i][jh * 4 + 2]);
                        acc[i][jh * 4 + 3] = fmaf(a, cv[jh].w, acc[i][jh * 4 + 3]);
                    }
                }
            }
        }
    }

    // scores + running argmin, k ascending per thread (jh-major)
    #pragma unroll
    for (int jh = 0; jh < 4; ++jh) {
        #pragma unroll
        for (int j = 0; j < 4; ++j) {
            int k = kbase + jh * 64 + tx * 4 + j;
            float cn = cnorm[k];
            #pragma unroll
            for (int i = 0; i < 8; ++i) {
                float t1 = xn[i] + cn;                  // fl32(xn + cn)
                float tw = 2.0f * acc[i][jh * 4 + j];   // exact x2
                float s  = t1 - tw;                     // fl32(t1 - tw)
                if (s < best[i]) { best[i] = s; bidx[i] = k; }
            }
        }
    }

    // cross-tx reduce (16 consecutive lanes share ty): strict <, tie -> lower index
    #pragma unroll
    for (int i = 0; i < 8; ++i) {
        float b = best[i];
        int   ix = bidx[i];
        #pragma unroll
        for (int m = 1; m <= 8; m <<= 1) {
            float ob = __shfl_xor(b, m);
            int   oi = __shfl_xor(ix, m);
            if (ob < b || (ob == b && oi < ix)) { b = ob; ix = oi; }
        }
        if (tx == 0) {
            int row = r0 + ty + 16 * i;
            unsigned int ub = __float_as_uint(b);
            ub = (ub & 0x80000000u) ? ~ub : (ub | 0x80000000u);  // order-preserving
            unsigned long long key = ((unsigned long long)ub << 32) | (unsigned int)ix;
            atomicMin(bestkey + row, key);   // min score, tie -> min k; deterministic
        }
    }
}

// ---------------- Kernel 3: gather + loss partials ----------------
__global__ void k_gather(const float* __restrict__ x, const float* __restrict__ cb,
                         const unsigned long long* __restrict__ bestkey,
                         float* __restrict__ qout, float* __restrict__ idx_out,
                         float* __restrict__ partial) {
    int row  = blockIdx.x * 4 + (threadIdx.x >> 6);
    int lane = threadIdx.x & 63;
    int bk = (int)(bestkey[row] & 0xFFFFFFFFull);
    if (lane == 0) idx_out[row] = (float)bk;
    const float4* crow = (const float4*)(cb + (size_t)bk * DIM);
    const float4* xrow = (const float4*)(x + (size_t)row * DIM);
    float4* qrow = (float4*)(qout + (size_t)row * DIM);
    float s = 0.f;
    #pragma unroll
    for (int it = 0; it < 2; ++it) {
        int d4 = lane + it * 64;
        float4 q = crow[d4];
        float4 xi = xrow[d4];
        qrow[d4] = q;
        float dx = q.x - xi.x; s += dx * dx;
        dx = q.y - xi.y; s += dx * dx;
        dx = q.z - xi.z; s += dx * dx;
        dx = q.w - xi.w; s += dx * dx;
    }
    #pragma unroll
    for (int m = 32; m >= 1; m >>= 1) s += __shfl_xor(s, m);
    __shared__ float ws4[4];
    if (lane == 0) ws4[threadIdx.x >> 6] = s;
    __syncthreads();
    if (threadIdx.x == 0)
        partial[blockIdx.x] = (ws4[0] + ws4[1]) + (ws4[2] + ws4[3]);
}

// ---------------- Kernel 4: deterministic final loss reduce ----------------
__global__ void k_loss(const float* __restrict__ partial, float* __restrict__ out_loss) {
    int t = threadIdx.x;   // 256 threads, 8192 partials
    double s = 0.0;
    #pragma unroll 4
    for (int i = 0; i < 32; ++i) s += (double)partial[t * 32 + i];
    #pragma unroll
    for (int m = 32; m >= 1; m >>= 1) s += __shfl_xor(s, m);
    __shared__ double sd[4];
    if ((t & 63) == 0) sd[t >> 6] = s;
    __syncthreads();
    if (t == 0) {
        double tot = (sd[0] + sd[1]) + (sd[2] + sd[3]);
        out_loss[0] = (float)(1.25 * tot / (double)Q_ELEMS);
    }
}

extern "C" void kernel_launch(void* const* d_in, const int* in_sizes, int n_in,
                              void* d_out, int out_size, void* d_ws, size_t ws_size,
                              hipStream_t stream) {
    const float* x  = (const float*)d_in[0];   // [32768, 512]
    const float* cb = (const float*)d_in[1];   // [4096, 512]
    float* out = (float*)d_out;

    char* ws = (char*)d_ws;
    unsigned long long* bestkey = (unsigned long long*)ws;  ws += (size_t)N_ROWS * 8;
    float* cnorm = (float*)ws;                              ws += (size_t)KCODES * 4;
    float* xnorm = (float*)ws;                              ws += (size_t)N_ROWS * 4;
    float* part  = (float*)ws;

    k_init<<<N_ROWS / 256, 256, 0, stream>>>(bestkey);
    k_cnorm<<<KCODES / 4, 256, 0, stream>>>(cb, cnorm);
    k_xnorm<<<N_ROWS / 4, 256, 0, stream>>>(x, xnorm);
    dim3 agrid(N_ROWS / BM, NPARTS);
    k_argmin<<<agrid, NTHR, 0, stream>>>(x, cb, cnorm, xnorm, bestkey);
    k_gather<<<N_ROWS / 4, 256, 0, stream>>>(x, cb, bestkey, out, out + IDX_OFF, part);
    k_loss<<<1, 256, 0, stream>>>(part, out + LOSS_OFF);
}

// Round 13
// 1640.515 us; speedup vs baseline: 1.3736x; 1.3736x over previous
//
#include <hip/hip_runtime.h>

// Problem constants (B=64, S=512, D=512, K=4096)
#define N_ROWS 32768          // B*S
#define DIM    512
#define KCODES 4096
#define NPARTS 16
#define KPART  (KCODES / NPARTS)    // 256 codes per K-split block
#define Q_ELEMS (N_ROWS * DIM)      // 16777216
#define LOSS_OFF Q_ELEMS            // 1 float
#define IDX_OFF (Q_ELEMS + 1)       // 32768 floats

// ---------------- Kernel 0: init packed argmin keys ----------------
__global__ void k_init(unsigned long long* __restrict__ bk) {
    int i = blockIdx.x * blockDim.x + threadIdx.x;
    if (i < N_ROWS) bk[i] = 0xFFFFFFFFFFFFFFFFull;
}

// ---------------- Kernel 1a: codebook norms ||c_k||^2 (fp32) ----------------
__global__ void k_cnorm(const float* __restrict__ cb, float* __restrict__ cnorm) {
    int wave = (blockIdx.x * blockDim.x + threadIdx.x) >> 6;
    int lane = threadIdx.x & 63;
    if (wave >= KCODES) return;
    const float4* row = (const float4*)(cb + (size_t)wave * DIM);
    float4 v1 = row[lane];
    float4 v2 = row[lane + 64];
    float s = v1.x*v1.x + v1.y*v1.y + v1.z*v1.z + v1.w*v1.w
            + v2.x*v2.x + v2.y*v2.y + v2.z*v2.z + v2.w*v2.w;
    #pragma unroll
    for (int m = 32; m >= 1; m >>= 1) s += __shfl_xor(s, m);
    if (lane == 0) cnorm[wave] = s;
}

// ---------------- Kernel 1b: input row norms ||x_n||^2 (fp32) ----------------
__global__ void k_xnorm(const float* __restrict__ x, float* __restrict__ xnorm) {
    int wave = (blockIdx.x * blockDim.x + threadIdx.x) >> 6;
    int lane = threadIdx.x & 63;
    if (wave >= N_ROWS) return;
    const float4* row = (const float4*)(x + (size_t)wave * DIM);
    float4 v1 = row[lane];
    float4 v2 = row[lane + 64];
    float s = v1.x*v1.x + v1.y*v1.y + v1.z*v1.z + v1.w*v1.w
            + v2.x*v2.x + v2.y*v2.y + v2.z*v2.z + v2.w*v2.w;
    #pragma unroll
    for (int m = 32; m >= 1; m >>= 1) s += __shfl_xor(s, m);
    if (lane == 0) xnorm[wave] = s;
}

// ---------------- Kernel 2: fp32-formula distance + argmin ----------------
// dist32(n,k) = fl32( fl32(xnorm + cnorm[k]) - fl32(2 * dot(n,k)) ), dot as a
// sequential-d fp32 fma chain — bit-identical per (n,k) to the passing rounds.
// FINAL (R9 structure, best measured 1659/1664 us, reproduced):
// 8x8 thread tile @256 threads, ds_write staging (0 conflicts), VGPR 112,
// 34.8KB LDS, NPARTS=16. Structural ceiling: LDS pipe @ ~12cyc/ds_read_b128
// bounds VALUBusy at 4296/(4*1656) = 65%; measured 64.6% = 99% of ceiling.
// Escape requires RC >= 6(R+C) tile (>=144 acc VGPRs -> <=2 waves/SIMD),
// measured twice (R6, R12) to collapse to ~47-49% busy from latency exposure.
// fp32-exactness (argmin on the ulp(512) grid) forbids MFMA.
// Part results merged via order-preserving packed atomicMin(u64):
// key = (monotone_uint(score)<<32) | k -> min score, tie -> min k.
#define BM 128
#define BN 128
#define BD 32
#define NTHR 256
#define NCH ((KPART / BN) * (DIM / BD))   // 2 kc * 16 dc = 32 chunks

__global__ __launch_bounds__(NTHR)
void k_argmin(const float* __restrict__ x, const float* __restrict__ cb,
              const float* __restrict__ cnorm, const float* __restrict__ xnorm,
              unsigned long long* __restrict__ bestkey) {
    __shared__ float xs[BM][BD + 4];   // stride 36 floats; measured 0 conflicts (R4/R5/R7/R9/R11)
    __shared__ float cs[BD][BN];       // transposed: cs[d][k]

    const int tid = threadIdx.x;
    const int ty = tid >> 4;           // 0..15
    const int tx = tid & 15;           // 0..15
    const int r0 = blockIdx.x * BM;
    const int kbase = blockIdx.y * KPART;

    // staging coords
    const int ck   = tid & 127;
    const int cdq0 = tid >> 7;         // 0..1

    float xn[8];
    #pragma unroll
    for (int i = 0; i < 8; ++i) xn[i] = xnorm[r0 + ty + 16 * i];

    float best[8];
    int   bidx[8];
    #pragma unroll
    for (int i = 0; i < 8; ++i) { best[i] = 3.4e38f; bidx[i] = kbase; }

    float acc[8][8];

    #pragma unroll 1
    for (int it = 0; it < NCH; ++it) {
        const int kc = it >> 4;            // 0..1
        const int dc = (it & 15) * BD;

        __syncthreads();   // previous chunk's readers done
        // stage x tile: 128 rows x 32 d (1024 float4, 4 per thread)
        #pragma unroll
        for (int s = 0; s < 4; ++s) {
            int f = tid + s * NTHR;
            int row = f >> 3;              // 0..127
            int dq  = f & 7;               // 0..7
            *(float4*)&xs[row][dq * 4] =
                *(const float4*)(x + (size_t)(r0 + row) * DIM + dc + dq * 4);
        }
        // stage code tile transposed: 128 codes x 32 d (0 conflicts measured)
        #pragma unroll
        for (int it2 = 0; it2 < 4; ++it2) {
            int dq = cdq0 + it2 * 2;
            float4 v = *(const float4*)(cb + (size_t)(kbase + kc * BN + ck) * DIM + dc + dq * 4);
            cs[dq * 4 + 0][ck] = v.x;
            cs[dq * 4 + 1][ck] = v.y;
            cs[dq * 4 + 2][ck] = v.z;
            cs[dq * 4 + 3][ck] = v.w;
        }
        __syncthreads();   // tile ready

        if ((it & 15) == 0) {
            #pragma unroll
            for (int i = 0; i < 8; ++i)
                #pragma unroll
                for (int j = 0; j < 8; ++j) acc[i][j] = 0.f;
        }

        // compute: 32 d-steps, d ascending (chain order = reference order)
        #pragma unroll
        for (int d4 = 0; d4 < 8; ++d4) {
            float4 xa[8];
            #pragma unroll
            for (int i = 0; i < 8; ++i)
                xa[i] = *(const float4*)&xs[ty + 16 * i][d4 * 4];
            #pragma unroll
            for (int dd = 0; dd < 4; ++dd) {
                int d = d4 * 4 + dd;
                float4 b0 = *(const float4*)&cs[d][tx * 4];
                float4 b1 = *(const float4*)&cs[d][64 + tx * 4];
                #pragma unroll
                for (int i = 0; i < 8; ++i) {
                    float a = (dd == 0) ? xa[i].x : (dd == 1) ? xa[i].y
                            : (dd == 2) ? xa[i].z : xa[i].w;   // dd compile-time
                    acc[i][0] = fmaf(a, b0.x, acc[i][0]);
                    acc[i][1] = fmaf(a, b0.y, acc[i][1]);
                    acc[i][2] = fmaf(a, b0.z, acc[i][2]);
                    acc[i][3] = fmaf(a, b0.w, acc[i][3]);
                    acc[i][4] = fmaf(a, b1.x, acc[i][4]);
                    acc[i][5] = fmaf(a, b1.y, acc[i][5]);
                    acc[i][6] = fmaf(a, b1.z, acc[i][6]);
                    acc[i][7] = fmaf(a, b1.w, acc[i][7]);
                }
            }
        }

        // end of a kc block: scores + running argmin, k ascending per thread
        if ((it & 15) == 15) {
            #pragma unroll
            for (int half = 0; half < 2; ++half) {
                #pragma unroll
                for (int j = 0; j < 4; ++j) {
                    int k = kbase + kc * BN + half * 64 + tx * 4 + j;
                    float cn = cnorm[k];
                    #pragma unroll
                    for (int i = 0; i < 8; ++i) {
                        float t1 = xn[i] + cn;                  // fl32(xn + cn)
                        float tw = 2.0f * acc[i][half * 4 + j]; // exact x2
                        float s  = t1 - tw;                     // fl32(t1 - tw)
                        if (s < best[i]) { best[i] = s; bidx[i] = k; }
                    }
                }
            }
        }
    }

    // cross-tx reduce (16 consecutive lanes share ty): strict <, tie -> lower index
    #pragma unroll
    for (int i = 0; i < 8; ++i) {
        float b = best[i];
        int   ix = bidx[i];
        #pragma unroll
        for (int m = 1; m <= 8; m <<= 1) {
            float ob = __shfl_xor(b, m);
            int   oi = __shfl_xor(ix, m);
            if (ob < b || (ob == b && oi < ix)) { b = ob; ix = oi; }
        }
        if (tx == 0) {
            int row = r0 + ty + 16 * i;
            unsigned int ub = __float_as_uint(b);
            ub = (ub & 0x80000000u) ? ~ub : (ub | 0x80000000u);  // order-preserving
            unsigned long long key = ((unsigned long long)ub << 32) | (unsigned int)ix;
            atomicMin(bestkey + row, key);   // min score, tie -> min k; deterministic
        }
    }
}

// ---------------- Kernel 3: gather + loss partials ----------------
__global__ void k_gather(const float* __restrict__ x, const float* __restrict__ cb,
                         const unsigned long long* __restrict__ bestkey,
                         float* __restrict__ qout, float* __restrict__ idx_out,
                         float* __restrict__ partial) {
    int row  = blockIdx.x * 4 + (threadIdx.x >> 6);
    int lane = threadIdx.x & 63;
    int bk = (int)(bestkey[row] & 0xFFFFFFFFull);
    if (lane == 0) idx_out[row] = (float)bk;
    const float4* crow = (const float4*)(cb + (size_t)bk * DIM);
    const float4* xrow = (const float4*)(x + (size_t)row * DIM);
    float4* qrow = (float4*)(qout + (size_t)row * DIM);
    float s = 0.f;
    #pragma unroll
    for (int it = 0; it < 2; ++it) {
        int d4 = lane + it * 64;
        float4 q = crow[d4];
        float4 xi = xrow[d4];
        qrow[d4] = q;
        float dx = q.x - xi.x; s += dx * dx;
        dx = q.y - xi.y; s += dx * dx;
        dx = q.z - xi.z; s += dx * dx;
        dx = q.w - xi.w; s += dx * dx;
    }
    #pragma unroll
    for (int m = 32; m >= 1; m >>= 1) s += __shfl_xor(s, m);
    __shared__ float ws4[4];
    if (lane == 0) ws4[threadIdx.x >> 6] = s;
    __syncthreads();
    if (threadIdx.x == 0)
        partial[blockIdx.x] = (ws4[0] + ws4[1]) + (ws4[2] + ws4[3]);
}

// ---------------- Kernel 4: deterministic final loss reduce ----------------
__global__ void k_loss(const float* __restrict__ partial, float* __restrict__ out_loss) {
    int t = threadIdx.x;   // 256 threads, 8192 partials
    double s = 0.0;
    #pragma unroll 4
    for (int i = 0; i < 32; ++i) s += (double)partial[t * 32 + i];
    #pragma unroll
    for (int m = 32; m >= 1; m >>= 1) s += __shfl_xor(s, m);
    __shared__ double sd[4];
    if ((t & 63) == 0) sd[t >> 6] = s;
    __syncthreads();
    if (t == 0) {
        double tot = (sd[0] + sd[1]) + (sd[2] + sd[3]);
        out_loss[0] = (float)(1.25 * tot / (double)Q_ELEMS);
    }
}

extern "C" void kernel_launch(void* const* d_in, const int* in_sizes, int n_in,
                              void* d_out, int out_size, void* d_ws, size_t ws_size,
                              hipStream_t stream) {
    const float* x  = (const float*)d_in[0];   // [32768, 512]
    const float* cb = (const float*)d_in[1];   // [4096, 512]
    float* out = (float*)d_out;

    char* ws = (char*)d_ws;
    unsigned long long* bestkey = (unsigned long long*)ws;  ws += (size_t)N_ROWS * 8;
    float* cnorm = (float*)ws;                              ws += (size_t)KCODES * 4;
    float* xnorm = (float*)ws;                              ws += (size_t)N_ROWS * 4;
    float* part  = (float*)ws;

    k_init<<<N_ROWS / 256, 256, 0, stream>>>(bestkey);
    k_cnorm<<<KCODES / 4, 256, 0, stream>>>(cb, cnorm);
    k_xnorm<<<N_ROWS / 4, 256, 0, stream>>>(x, xnorm);
    dim3 agrid(N_ROWS / BM, NPARTS);
    k_argmin<<<agrid, NTHR, 0, stream>>>(x, cb, cnorm, xnorm, bestkey);
    k_gather<<<N_ROWS / 4, 256, 0, stream>>>(x, cb, bestkey, out, out + IDX_OFF, part);
    k_loss<<<1, 256, 0, stream>>>(part, out + LOSS_OFF);
}